// Round 3
// baseline (1047.803 us; speedup 1.0000x reference)
//
#include <hip/hip_runtime.h>
#include <hip/hip_bf16.h>
#include <type_traits>

typedef unsigned short u16;
typedef unsigned int u32;
typedef unsigned long long u64;
typedef u16 u16x8 __attribute__((ext_vector_type(8)));
typedef __bf16 bf16x8 __attribute__((ext_vector_type(8)));
typedef float f32x4 __attribute__((ext_vector_type(4)));

#define D_FF   11008
#define NROWS  2048
#define NDIM   4096
#define KTOK   2201
#define KCORE  2201
#define NSPLIT 2201
#define TARGET 4403
#define NREM   (D_FF - NSPLIT)   // 8807

// f32 -> bf16 round-to-nearest-even (inputs are finite; no NaN path needed)
__device__ __forceinline__ u16 f2bf(float f) {
  u32 u = __float_as_uint(f);
  u32 r = u + 0x7fffu + ((u >> 16) & 1u);
  return (u16)(r >> 16);
}

// ---------------------------------------------------------------------------
// Kernel A: per-row exact top-KTOK membership -> counts[f] increments.
// f32 values mapped to 32-bit monotonic keys; 4-pass byte-radix histogram
// finds the rank-KTOK threshold key T exactly. Elements > T selected; first
// `need` elements == T (ascending index) replicate lax.top_k tie-break.
// ---------------------------------------------------------------------------
__global__ __launch_bounds__(256) void row_topk_counts(const float* __restrict__ x,
                                                       int* __restrict__ counts) {
  const int row = blockIdx.x;
  const int tid = threadIdx.x;
  __shared__ u32 keys[D_FF];        // 44 KB
  __shared__ int hist[256];
  __shared__ u32 s_pref;
  __shared__ int s_r;

  const float* xr = x + (size_t)row * D_FF;
  for (int f = tid; f < D_FF; f += 256) {
    u32 b = __float_as_uint(xr[f]);
    keys[f] = (b & 0x80000000u) ? ~b : (b | 0x80000000u);
  }
  if (tid == 0) { s_pref = 0; s_r = KTOK; }
  __syncthreads();

  #pragma unroll
  for (int shift = 24; shift >= 0; shift -= 8) {
    hist[tid] = 0;
    __syncthreads();
    const u64 pref = (u64)s_pref;
    for (int f = tid; f < D_FF; f += 256) {
      u32 k = keys[f];
      if (((u64)k >> (shift + 8)) == pref)   // u64 shift: safe at shift==24
        atomicAdd(&hist[(k >> shift) & 0xffu], 1);
    }
    __syncthreads();
    if (tid == 0) {
      int r = s_r, cum = 0;
      for (int b = 255; b >= 0; --b) {
        int c = hist[b];
        if (cum + c >= r) { s_pref = (s_pref << 8) | (u32)b; s_r = r - cum; break; }
        cum += c;
      }
    }
    __syncthreads();
  }

  const u32 T = s_pref;
  const int need = s_r;          // how many ==T elements to take (lowest idx)
  for (int f = tid; f < D_FF; f += 256)
    if (keys[f] > T) atomicAdd(&counts[f], 1);
  if (tid < 64) {
    int taken = 0;
    for (int base = 0; base < D_FF; base += 64) {
      int f = base + tid;
      bool eq = (keys[f] == T);
      u64 m = __ballot(eq);
      int before = __popcll(m & ((1ull << tid) - 1ull));
      if (eq && (taken + before) < need) atomicAdd(&counts[f], 1);
      taken += __popcll(m);
      if (taken >= need) break;
    }
  }
}

// ---------------------------------------------------------------------------
// Kernel B (single block): core = top-KCORE of counts (tie-break low index),
// union with model_neurons[:NSPLIT], then coef[f] = x_dec[pos of f in idx_all].
// Writes both f32 and bf16 coef vectors.
// ---------------------------------------------------------------------------
__global__ __launch_bounds__(256) void build_coef(const int* __restrict__ counts,
                                                  const int* __restrict__ mn,
                                                  const float* __restrict__ xdec,
                                                  float* __restrict__ coef_f,
                                                  u16* __restrict__ coef_h) {
  const int tid = threadIdx.x;
  __shared__ int hist[2049];
  __shared__ unsigned char uni[D_FF];
  __shared__ int cs[256];
  __shared__ int s_Tc, s_need, s_U;

  for (int i = tid; i < 2049; i += 256) hist[i] = 0;
  __syncthreads();
  for (int f = tid; f < D_FF; f += 256) atomicAdd(&hist[counts[f]], 1);
  __syncthreads();
  if (tid == 0) {
    int cum = 0, Tc = 0;
    for (int b = 2048; b >= 0; --b) {
      int c = hist[b];
      if (cum + c >= KCORE) { Tc = b; break; }
      cum += c;
    }
    s_Tc = Tc;
    s_need = KCORE - cum;
  }
  __syncthreads();
  const int Tc = s_Tc;
  const int need = s_need;
  for (int f = tid; f < D_FF; f += 256) uni[f] = (counts[f] > Tc) ? 1 : 0;
  __syncthreads();
  if (tid < 64) {
    int taken = 0;
    for (int base = 0; base < D_FF; base += 64) {
      int f = base + tid;
      bool eq = (counts[f] == Tc);
      u64 m = __ballot(eq);
      int before = __popcll(m & ((1ull << tid) - 1ull));
      if (eq && (taken + before) < need) uni[f] = 1;
      taken += __popcll(m);
      if (taken >= need) break;
    }
  }
  __syncthreads();
  for (int j = tid; j < NSPLIT; j += 256) uni[mn[j]] = 1;
  __syncthreads();

  // union members (ascending f) occupy positions 0..U-1 of idx_all
  {
    int s = 0;
    const int base = tid * 43;           // 256*43 == 11008
    for (int i = 0; i < 43; ++i) s += uni[base + i];
    cs[tid] = s;
  }
  __syncthreads();
  if (tid == 0) {
    int run = 0;
    for (int t = 0; t < 256; ++t) { int v = cs[t]; cs[t] = run; run += v; }
    s_U = run;
  }
  __syncthreads();
  {
    int k = cs[tid];
    const int base = tid * 43;
    for (int i = 0; i < 43; ++i) {
      int f = base + i;
      if (uni[f]) {                      // U <= 4402 < TARGET always
        float v = xdec[k];
        coef_f[f] = v;
        coef_h[f] = f2bf(v);
        ++k;
      }
    }
  }
  __syncthreads();
  const int U = s_U;

  // remaining TARGET-U slots from rem (model_neurons order, non-union only)
  int s2 = 0;
  const int j0 = tid * 35;               // 256*35 >= 8807
  const int j1 = (j0 + 35 < NREM) ? (j0 + 35) : NREM;
  for (int j = j0; j < j1; ++j) s2 += uni[mn[NSPLIT + j]] ? 0 : 1;
  __syncthreads();
  cs[tid] = s2;
  __syncthreads();
  if (tid == 0) {
    int run = 0;
    for (int t = 0; t < 256; ++t) { int v = cs[t]; cs[t] = run; run += v; }
  }
  __syncthreads();
  {
    int k = U + cs[tid];
    for (int j = j0; j < j1; ++j) {
      int f = mn[NSPLIT + j];
      if (!uni[f]) {
        if (k < TARGET) {
          float v = xdec[k];
          coef_f[f] = v;
          coef_h[f] = f2bf(v);
        }
        ++k;
      }
    }
  }
}

// ---------------------------------------------------------------------------
// f32 -> bf16 bulk convert (8 elements / thread, 32B read / 16B write)
// ---------------------------------------------------------------------------
__global__ __launch_bounds__(256) void cvt_bf16(const float* __restrict__ in,
                                                u16* __restrict__ outp, int n8) {
  int i = blockIdx.x * 256 + threadIdx.x;
  if (i >= n8) return;
  const float4* p = (const float4*)in + 2 * (size_t)i;
  float4 a = p[0], b = p[1];
  u16x8 h;
  h[0] = f2bf(a.x); h[1] = f2bf(a.y); h[2] = f2bf(a.z); h[3] = f2bf(a.w);
  h[4] = f2bf(b.x); h[5] = f2bf(b.y); h[6] = f2bf(b.z); h[7] = f2bf(b.w);
  *((u16x8*)outp + i) = h;
}

__device__ __forceinline__ u16x8 pack8(float4 a, float4 b) {
  u16x8 h;
  h[0] = f2bf(a.x); h[1] = f2bf(a.y); h[2] = f2bf(a.z); h[3] = f2bf(a.w);
  h[4] = f2bf(b.x); h[5] = f2bf(b.y); h[6] = f2bf(b.z); h[7] = f2bf(b.w);
  return h;
}

// ---------------------------------------------------------------------------
// GEMM: C(2049x4096) = A(2049x11008) * W(4096x11008)^T, f32 out.
// Row 2048 of A is the coef vector. 128x128 tile, BK=32, 4 waves each
// computing 64x64 via 4x4 mfma_f32_16x16x32_bf16, classic staging.
// CVT=true: inputs f32, convert during staging. CVT=false: inputs bf16.
// ---------------------------------------------------------------------------
template <bool CVT>
__global__ __launch_bounds__(256) void gemm_bt(const void* __restrict__ xv,
                                               const void* __restrict__ wv,
                                               const void* __restrict__ cv,
                                               float* __restrict__ out) {
  using ET = typename std::conditional<CVT, float, u16>::type;
  __shared__ alignas(16) u16 As[128 * 32];
  __shared__ alignas(16) u16 Bs[128 * 32];
  const int tid  = threadIdx.x;
  const int lane = tid & 63;
  const int bn   = blockIdx.x;   // 0..31
  const int bm   = blockIdx.y;   // 0..16
  const int wid  = tid >> 6;
  const int wm   = wid & 1;
  const int wn   = wid >> 1;

  // staging: thread t covers tile row t>>2 (and +64), k-elems (t&3)*8..+8
  const int r0 = tid >> 2;
  const int kk = (tid & 3) * 8;

  const ET* ag[2];
  const ET* bg[2];
  u16* al[2];
  u16* bl[2];
  #pragma unroll
  for (int p = 0; p < 2; ++p) {
    const int rl = p * 64 + r0;
    int R = bm * 128 + rl;
    if (R > NROWS) R = NROWS;    // pad rows re-load the coef row; never stored
    ag[p] = ((R == NROWS) ? (const ET*)cv : ((const ET*)xv + (size_t)R * D_FF)) + kk;
    bg[p] = (const ET*)wv + (size_t)(bn * 128 + rl) * D_FF + kk;
    al[p] = &As[rl * 32 + kk];
    bl[p] = &Bs[rl * 32 + kk];
  }

  f32x4 acc[4][4] = {};
  const int r16 = lane & 15;
  const int kg  = (lane >> 4) * 8;

  for (int k0 = 0; k0 < D_FF; k0 += 32) {
    u16x8 sa[2], sb[2];
    #pragma unroll
    for (int p = 0; p < 2; ++p) {
      if (CVT) {
        const float* pa = (const float*)ag[p] + k0;
        const float* pb = (const float*)bg[p] + k0;
        sa[p] = pack8(*(const float4*)pa, *(const float4*)(pa + 4));
        sb[p] = pack8(*(const float4*)pb, *(const float4*)(pb + 4));
      } else {
        sa[p] = *(const u16x8*)((const u16*)ag[p] + k0);
        sb[p] = *(const u16x8*)((const u16*)bg[p] + k0);
      }
    }
    __syncthreads();               // prior iteration's ds_reads complete
    #pragma unroll
    for (int p = 0; p < 2; ++p) {
      *(u16x8*)al[p] = sa[p];
      *(u16x8*)bl[p] = sb[p];
    }
    __syncthreads();               // staging visible to all waves
    bf16x8 af[4], bf[4];
    #pragma unroll
    for (int mi = 0; mi < 4; ++mi)
      af[mi] = *(const bf16x8*)&As[(wm * 64 + mi * 16 + r16) * 32 + kg];
    #pragma unroll
    for (int ni = 0; ni < 4; ++ni)
      bf[ni] = *(const bf16x8*)&Bs[(wn * 64 + ni * 16 + r16) * 32 + kg];
    #pragma unroll
    for (int mi = 0; mi < 4; ++mi)
      #pragma unroll
      for (int ni = 0; ni < 4; ++ni)
        acc[mi][ni] = __builtin_amdgcn_mfma_f32_16x16x32_bf16(af[mi], bf[ni],
                                                              acc[mi][ni], 0, 0, 0);
  }

  // C/D layout (m89-verified): col = lane&15, row = (lane>>4)*4 + reg
  #pragma unroll
  for (int mi = 0; mi < 4; ++mi) {
    const int rbase = bm * 128 + wm * 64 + mi * 16 + (lane >> 4) * 4;
    #pragma unroll
    for (int ni = 0; ni < 4; ++ni) {
      const int c = bn * 128 + wn * 64 + ni * 16 + r16;
      #pragma unroll
      for (int q = 0; q < 4; ++q) {
        const int r = rbase + q;
        if (r <= NROWS)
          out[(size_t)r * NDIM + c] = acc[mi][ni][q];
      }
    }
  }
}

extern "C" void kernel_launch(void* const* d_in, const int* in_sizes, int n_in,
                              void* d_out, int out_size, void* d_ws, size_t ws_size,
                              hipStream_t stream) {
  (void)in_sizes; (void)n_in; (void)out_size;
  const float* x    = (const float*)d_in[0];   // f32 (1,2048,11008)
  const float* w    = (const float*)d_in[1];   // f32 (4096,11008)
  const float* xdec = (const float*)d_in[2];   // f32 (4403)
  const int*   mn   = (const int*)d_in[3];     // int32 (11008)
  float* out = (float*)d_out;                  // f32 (2049*4096)

  char* ws = (char*)d_ws;
  int*   counts = (int*)ws;                        // 44032 B
  float* coef_f = (float*)(ws + 44032);            // 44032 B
  u16*   coef_h = (u16*)(ws + 88064);              // 22016 B
  u16*   xb     = (u16*)(ws + 110080);             // 45,088,768 B
  u16*   wb     = (u16*)(ws + 110080 + 45088768ull); // 90,177,536 B
  const size_t need_fast = 110080ull + 45088768ull + 90177536ull;

  hipMemsetAsync(d_ws, 0, 110080, stream);
  row_topk_counts<<<NROWS, 256, 0, stream>>>(x, counts);
  build_coef<<<1, 256, 0, stream>>>(counts, mn, xdec, coef_f, coef_h);

  if (ws_size >= need_fast) {
    cvt_bf16<<<(NROWS * D_FF / 8 + 255) / 256, 256, 0, stream>>>(x, xb, NROWS * D_FF / 8);
    cvt_bf16<<<(NDIM * D_FF / 8 + 255) / 256, 256, 0, stream>>>(w, wb, NDIM * D_FF / 8);
    gemm_bt<false><<<dim3(32, 17), 256, 0, stream>>>(xb, wb, coef_h, out);
  } else {
    gemm_bt<true><<<dim3(32, 17), 256, 0, stream>>>(x, w, coef_f, out);
  }
}